// Round 12
// baseline (89.404 us; speedup 1.0000x reference)
//
#include <hip/hip_runtime.h>
#include <hip/hip_bf16.h>

// DenseEnergyLoss on MI355X. N=4, K=21, H=W=128 -> OH=OW=64, P=4096.
// loss = 0.1*(-0.5)/(N*P) * sum_{n,p,q} exp(-0.5*max(|f_p-f_q|^2,0)) * gate_p * <seg_p, seg_q>
// Symmetrized: gate_p -> (gate_p+gate_q)/2; upper-triangular 128x128 tile-pairs,
// diag 0.5 / off-diag 1.0 (x2 folded).
// R12: ATTRIBUTION PROBE. Energy body (identical to R11) executed twice via a
// non-unrolled rep loop; q-pointers pass through an empty asm barrier so
// LICM/CSE cannot hoist the work; partial scaled by 0.5 (numerically ~exact).
// Purpose: (a) dT = E directly (R2- vs R7-derived attributions disagree 17 vs
// 28us); (b) 2E ~ 34-56us cracks the top-5 fill floor (~41us) exposing energy's
// VGPR/Occupancy/VALUBusy/MfmaUtil counters for the first time.
// comb row (32 f16): ch0..20 seg_m, ch21..23=0, ch24..28 = f*sqrt(log2e),
// ch29 = cs(f16), ch30 = 1.0, ch31 = 0.  B quad3 patched (j5<-1, j6<-cs, j7<-0):
//   C1 = acomb x bcomb = G + log2e*fp.fq + csp + csq ; arg = C1 - G.
// MFMA layouts (HW-verified m89/m120): A/B point=lane&15, k=(lane>>4)*8+j;
// C/D col=lane&15, row=(lane>>4)*4+reg.

constexpr int N_ = 4, K_ = 21, H_ = 128, W_ = 128, P_ = 4096;
constexpr int T_ = 128;                  // tile size (p and q)
constexpr int NT = P_ / T_;              // 32 tiles per dim
constexpr int NTRI = NT * (NT + 1) / 2;  // 528 upper-tri tile pairs per n
constexpr int NBLK = NTRI * N_;          // 2112 energy blocks
constexpr float INV_RGB = 1.0f / 15.0f;
constexpr float INV_XY = 1.0f / 40.0f;   // 1/(SIGMA_XY*SCALE)
constexpr float SQRT_LOG2E = 1.2011224087864498f; // sqrt(log2(e))
constexpr float OUT_SCALE = -0.05f / 16384.0f;    // 0.1 * -0.5 / (N*P)

typedef _Float16 half8 __attribute__((ext_vector_type(8)));
typedef float floatx4 __attribute__((ext_vector_type(4)));

__global__ void __launch_bounds__(64) prep_kernel(
    const float* __restrict__ img, const float* __restrict__ seg,
    const float* __restrict__ roi, const float* __restrict__ lab,
    _Float16* __restrict__ comb, float* __restrict__ gate) {
  int idx = blockIdx.x * 64 + threadIdx.x; // n*P + p ; one wave == one (n,y) row
  int n = idx >> 12;
  int p = idx & (P_ - 1);
  int y = p >> 6, x = p & 63;
  int iy = 2 * y, ix = 2 * x;
  const size_t hw = (size_t)H_ * W_;

  float r = roi[(size_t)n * hw + iy * W_ + ix];
  float lb = lab[(size_t)n * hw + iy * W_ + ix];
  bool unlabeled = ((int)lb == 255);

  const float* sb = seg + (size_t)n * K_ * hw + (size_t)iy * W_ + ix;
  _Float16 ch[32];
  float mx = -1e30f;
#pragma unroll
  for (int k = 0; k < K_; k++) {
    const float* s = sb + (size_t)k * hw;
    float v = 0.25f * (s[0] + s[1] + s[W_] + s[W_ + 1]); // bilinear @0.5 == 2x2 avg
    mx = fmaxf(mx, v);
    ch[k] = (_Float16)(v * r); // seg_m = seg_s * roi, rounded to f16
  }
  ch[21] = (_Float16)0.0f; ch[22] = (_Float16)0.0f; ch[23] = (_Float16)0.0f;

  const float* ib = img + (size_t)n * 3 * hw + (size_t)iy * W_ + ix;
  ch[24] = (_Float16)((float)x * INV_XY * SQRT_LOG2E);
  ch[25] = (_Float16)((float)y * INV_XY * SQRT_LOG2E);
  ch[26] = (_Float16)(ib[0] * INV_RGB * SQRT_LOG2E);
  ch[27] = (_Float16)(ib[hw] * INV_RGB * SQRT_LOG2E);
  ch[28] = (_Float16)(ib[2 * hw] * INV_RGB * SQRT_LOG2E);

  // cs from the ROUNDED, pre-scaled channels: arg_diag = sum(ch^2) + 2*cs ~ 0.
  float sq = 0.0f;
#pragma unroll
  for (int j = 24; j < 29; j++) { float v = (float)ch[j]; sq = fmaf(v, v, sq); }
  ch[29] = (_Float16)(-0.5f * sq);
  ch[30] = (_Float16)1.0f;
  ch[31] = (_Float16)0.0f;

  float4* dst = (float4*)(comb + (size_t)idx * 32);
  const float4* src = (const float4*)ch;
#pragma unroll
  for (int j = 0; j < 4; j++) dst[j] = src[j];

  float g = unlabeled ? 1.0f : (r - mx);
  gate[idx] = fmaxf(g, 0.0f);
}

__global__ void __launch_bounds__(256, 4) energy_kernel(
    const _Float16* __restrict__ comb, const float* __restrict__ gate,
    float* __restrict__ partial) {
  // Decode upper-triangular tile pair (pb <= qb) from blockIdx.x in [0, 528).
  int t = blockIdx.x;
  int pb = 0;
  while (t >= NT - pb) { t -= NT - pb; pb++; }
  int qb = pb + t;
  int n = blockIdx.y;
  int tid = threadIdx.x;
  int lane = tid & 63, wave = tid >> 6;
  int m = lane & 15, quad = lane >> 4;

  const _Float16* combn = comb + (size_t)n * P_ * 32;
  const float* gaten = gate + (size_t)n * P_;
  const half8 zfrag = {};

  // A-side preload (small): 2 p-strips + p-gates.
  half8 acomb[2], aseg0[2];
  float gpv[2][4];
#pragma unroll
  for (int s = 0; s < 2; s++) {
    int prow = pb * T_ + (2 * wave + s) * 16 + m;
    acomb[s] = *(const half8*)(combn + (size_t)prow * 32 + quad * 8);
    aseg0[s] = (quad == 3) ? zfrag : acomb[s]; // kill feat/cs channels for G
#pragma unroll
    for (int r = 0; r < 4; r++)
      gpv[s][r] = gaten[pb * T_ + (2 * wave + s) * 16 + quad * 4 + r];
  }

  bool patch = (quad == 3);
  float acc = 0.0f;

  // PROBE: run the identical q-sweep twice; opaque pointers stop hoisting.
#pragma unroll 1
  for (int rep = 0; rep < 2; rep++) {
    const _Float16* qcomb = combn + (size_t)qb * T_ * 32;
    const float* qgate = gaten + qb * T_;
    __asm__ volatile("" : "+s"(qcomb), "+s"(qgate));

#pragma unroll
    for (int qs = 0; qs < 8; qs++) {
      half8 b = *(const half8*)(qcomb + (size_t)(qs * 16 + m) * 32 + quad * 8);
      if (patch) {
        _Float16 cs = b[5];           // stored ch29 = cs(q)
        b[5] = (_Float16)1.0f;        // pairs with A's csp
        b[6] = cs;                    // pairs with A's 1.0
        b[7] = (_Float16)0.0f;
      }
      float gq = qgate[qs * 16 + m];
#pragma unroll
      for (int s = 0; s < 2; s++) {
        floatx4 C1 = {0.0f, 0.0f, 0.0f, 0.0f};
        floatx4 G = {0.0f, 0.0f, 0.0f, 0.0f};
        C1 = __builtin_amdgcn_mfma_f32_16x16x32_f16(acomb[s], b, C1, 0, 0, 0);
        G = __builtin_amdgcn_mfma_f32_16x16x32_f16(aseg0[s], b, G, 0, 0, 0);
#pragma unroll
        for (int r = 0; r < 4; r++) {
          float arg = C1[r] - G[r];              // = log2e*fp.fq + csp + csq
          float A = __builtin_amdgcn_exp2f(arg);
          A = fminf(A, 1.0f);
          acc = fmaf(A * G[r], gpv[s][r] + gq, acc);
        }
      }
    }
  }

  // Reduce within block; store partial (x0.5: work was done twice).
#pragma unroll
  for (int off = 32; off > 0; off >>= 1) acc += __shfl_down(acc, off, 64);
  __shared__ float wsum[4];
  if (lane == 0) wsum[wave] = acc;
  __syncthreads();
  if (tid == 0) {
    float s = (wsum[0] + wsum[1]) + (wsum[2] + wsum[3]);
    float wb = (pb == qb) ? 0.25f : 0.5f; // 0.5x duplication factor folded
    partial[blockIdx.y * NTRI + blockIdx.x] = s * wb;
  }
}

__global__ void __launch_bounds__(256) reduce_kernel(
    const float* __restrict__ partial, float* __restrict__ out) {
  int tid = threadIdx.x;
  float acc = 0.0f;
  for (int i = tid; i < NBLK; i += 256) acc += partial[i];
#pragma unroll
  for (int off = 32; off > 0; off >>= 1) acc += __shfl_down(acc, off, 64);
  __shared__ float wsum[4];
  int lane = tid & 63, wave = tid >> 6;
  if (lane == 0) wsum[wave] = acc;
  __syncthreads();
  if (tid == 0) {
    float s = (wsum[0] + wsum[1]) + (wsum[2] + wsum[3]);
    out[0] = s * OUT_SCALE;
  }
}

extern "C" void kernel_launch(void* const* d_in, const int* in_sizes, int n_in,
                              void* d_out, int out_size, void* d_ws, size_t ws_size,
                              hipStream_t stream) {
  const float* images = (const float*)d_in[0];
  const float* segs = (const float*)d_in[1];
  const float* rois = (const float*)d_in[2];
  const float* labels = (const float*)d_in[3];
  float* out = (float*)d_out;

  char* ws = (char*)d_ws;
  _Float16* comb = (_Float16*)ws;                                  // 1 MB
  float* gate = (float*)(ws + (size_t)N_ * P_ * 32 * 2);           // 64 KB
  float* partial = (float*)(ws + (size_t)N_ * P_ * 32 * 2 +
                            (size_t)N_ * P_ * sizeof(float));      // 8.25 KB

  prep_kernel<<<dim3(N_ * P_ / 64), dim3(64), 0, stream>>>(
      images, segs, rois, labels, comb, gate);
  energy_kernel<<<dim3(NTRI, N_), dim3(256), 0, stream>>>(comb, gate, partial);
  reduce_kernel<<<dim3(1), dim3(256), 0, stream>>>(partial, out);
}

// Round 13
// 79.774 us; speedup vs baseline: 1.1207x; 1.1207x over previous
//
#include <hip/hip_runtime.h>
#include <hip/hip_bf16.h>

// DenseEnergyLoss on MI355X. N=4, K=21, H=W=128 -> OH=OW=64, P=4096.
// loss = 0.1*(-0.5)/(N*P) * sum_{n,p,q} exp(-0.5*max(|f_p-f_q|^2,0)) * gate_p * <seg_p, seg_q>
// Symmetrized: gate_p -> (gate_p+gate_q)/2; upper-triangular 128x128 tile-pairs,
// diag 0.5 / off-diag 1.0 (x2 folded).
// R13: revert R12's 2x duplication probe -> final = R11 configuration.
// Probe result (R12): dT = 9.3us => energy ~= 9.3us, vs ~41us harness ws
// re-poison fill (268MB @ 82% HBM peak, memory-bound, not controllable) and
// ~30us fixed replay machinery. Energy is ~12% of total; remaining headroom
// <= 5us. Structure: MFMA-based pair kernel --
// comb row (32 f16): ch0..20 seg_m, ch21..23=0, ch24..28 = f*sqrt(log2e),
// ch29 = cs(f16), ch30 = 1.0, ch31 = 0.  B quad3 patched (j5<-1, j6<-cs, j7<-0):
//   C1 = acomb x bcomb = G + log2e*fp.fq + csp + csq ; arg = C1 - G.
// MFMA layouts (HW-verified m89/m120): A/B point=lane&15, k=(lane>>4)*8+j;
// C/D col=lane&15, row=(lane>>4)*4+reg.

constexpr int N_ = 4, K_ = 21, H_ = 128, W_ = 128, P_ = 4096;
constexpr int T_ = 128;                  // tile size (p and q)
constexpr int NT = P_ / T_;              // 32 tiles per dim
constexpr int NTRI = NT * (NT + 1) / 2;  // 528 upper-tri tile pairs per n
constexpr int NBLK = NTRI * N_;          // 2112 energy blocks
constexpr float INV_RGB = 1.0f / 15.0f;
constexpr float INV_XY = 1.0f / 40.0f;   // 1/(SIGMA_XY*SCALE)
constexpr float SQRT_LOG2E = 1.2011224087864498f; // sqrt(log2(e))
constexpr float OUT_SCALE = -0.05f / 16384.0f;    // 0.1 * -0.5 / (N*P)

typedef _Float16 half8 __attribute__((ext_vector_type(8)));
typedef float floatx4 __attribute__((ext_vector_type(4)));

__global__ void __launch_bounds__(64) prep_kernel(
    const float* __restrict__ img, const float* __restrict__ seg,
    const float* __restrict__ roi, const float* __restrict__ lab,
    _Float16* __restrict__ comb, float* __restrict__ gate) {
  int idx = blockIdx.x * 64 + threadIdx.x; // n*P + p ; one wave == one (n,y) row
  int n = idx >> 12;
  int p = idx & (P_ - 1);
  int y = p >> 6, x = p & 63;
  int iy = 2 * y, ix = 2 * x;
  const size_t hw = (size_t)H_ * W_;

  float r = roi[(size_t)n * hw + iy * W_ + ix];
  float lb = lab[(size_t)n * hw + iy * W_ + ix];
  bool unlabeled = ((int)lb == 255);

  const float* sb = seg + (size_t)n * K_ * hw + (size_t)iy * W_ + ix;
  _Float16 ch[32];
  float mx = -1e30f;
#pragma unroll
  for (int k = 0; k < K_; k++) {
    const float* s = sb + (size_t)k * hw;
    float v = 0.25f * (s[0] + s[1] + s[W_] + s[W_ + 1]); // bilinear @0.5 == 2x2 avg
    mx = fmaxf(mx, v);
    ch[k] = (_Float16)(v * r); // seg_m = seg_s * roi, rounded to f16
  }
  ch[21] = (_Float16)0.0f; ch[22] = (_Float16)0.0f; ch[23] = (_Float16)0.0f;

  const float* ib = img + (size_t)n * 3 * hw + (size_t)iy * W_ + ix;
  ch[24] = (_Float16)((float)x * INV_XY * SQRT_LOG2E);
  ch[25] = (_Float16)((float)y * INV_XY * SQRT_LOG2E);
  ch[26] = (_Float16)(ib[0] * INV_RGB * SQRT_LOG2E);
  ch[27] = (_Float16)(ib[hw] * INV_RGB * SQRT_LOG2E);
  ch[28] = (_Float16)(ib[2 * hw] * INV_RGB * SQRT_LOG2E);

  // cs from the ROUNDED, pre-scaled channels: arg_diag = sum(ch^2) + 2*cs ~ 0.
  float sq = 0.0f;
#pragma unroll
  for (int j = 24; j < 29; j++) { float v = (float)ch[j]; sq = fmaf(v, v, sq); }
  ch[29] = (_Float16)(-0.5f * sq);
  ch[30] = (_Float16)1.0f;
  ch[31] = (_Float16)0.0f;

  float4* dst = (float4*)(comb + (size_t)idx * 32);
  const float4* src = (const float4*)ch;
#pragma unroll
  for (int j = 0; j < 4; j++) dst[j] = src[j];

  float g = unlabeled ? 1.0f : (r - mx);
  gate[idx] = fmaxf(g, 0.0f);
}

__global__ void __launch_bounds__(256, 4) energy_kernel(
    const _Float16* __restrict__ comb, const float* __restrict__ gate,
    float* __restrict__ partial) {
  // Decode upper-triangular tile pair (pb <= qb) from blockIdx.x in [0, 528).
  int t = blockIdx.x;
  int pb = 0;
  while (t >= NT - pb) { t -= NT - pb; pb++; }
  int qb = pb + t;
  int n = blockIdx.y;
  int tid = threadIdx.x;
  int lane = tid & 63, wave = tid >> 6;
  int m = lane & 15, quad = lane >> 4;

  const _Float16* combn = comb + (size_t)n * P_ * 32;
  const float* gaten = gate + (size_t)n * P_;
  const half8 zfrag = {};

  // A-side preload (small): 2 p-strips + p-gates.
  half8 acomb[2], aseg0[2];
  float gpv[2][4];
#pragma unroll
  for (int s = 0; s < 2; s++) {
    int prow = pb * T_ + (2 * wave + s) * 16 + m;
    acomb[s] = *(const half8*)(combn + (size_t)prow * 32 + quad * 8);
    aseg0[s] = (quad == 3) ? zfrag : acomb[s]; // kill feat/cs channels for G
#pragma unroll
    for (int r = 0; r < 4; r++)
      gpv[s][r] = gaten[pb * T_ + (2 * wave + s) * 16 + quad * 4 + r];
  }

  const _Float16* qcomb = combn + (size_t)qb * T_ * 32; // wave-independent
  const float* qgate = gaten + qb * T_;
  bool patch = (quad == 3);

  // Fully unrolled (compile-time indices -- R7 lesson) with B-side streamed:
  // only ~2-3 fragments live at once, VGPR <= 128 (4 waves/SIMD).
  float acc = 0.0f;
#pragma unroll
  for (int qs = 0; qs < 8; qs++) {
    half8 b = *(const half8*)(qcomb + (size_t)(qs * 16 + m) * 32 + quad * 8);
    if (patch) {
      _Float16 cs = b[5];           // stored ch29 = cs(q)
      b[5] = (_Float16)1.0f;        // pairs with A's csp
      b[6] = cs;                    // pairs with A's 1.0
      b[7] = (_Float16)0.0f;
    }
    float gq = qgate[qs * 16 + m];
#pragma unroll
    for (int s = 0; s < 2; s++) {
      floatx4 C1 = {0.0f, 0.0f, 0.0f, 0.0f};
      floatx4 G = {0.0f, 0.0f, 0.0f, 0.0f};
      C1 = __builtin_amdgcn_mfma_f32_16x16x32_f16(acomb[s], b, C1, 0, 0, 0);
      G = __builtin_amdgcn_mfma_f32_16x16x32_f16(aseg0[s], b, G, 0, 0, 0);
#pragma unroll
      for (int r = 0; r < 4; r++) {
        float arg = C1[r] - G[r];              // = log2e*fp.fq + csp + csq
        float A = __builtin_amdgcn_exp2f(arg);
        A = fminf(A, 1.0f);
        acc = fmaf(A * G[r], gpv[s][r] + gq, acc);
      }
    }
  }

  // Reduce within block; store partial to a distinct address (no atomics).
#pragma unroll
  for (int off = 32; off > 0; off >>= 1) acc += __shfl_down(acc, off, 64);
  __shared__ float wsum[4];
  if (lane == 0) wsum[wave] = acc;
  __syncthreads();
  if (tid == 0) {
    float s = (wsum[0] + wsum[1]) + (wsum[2] + wsum[3]);
    float wb = (pb == qb) ? 0.5f : 1.0f;
    partial[blockIdx.y * NTRI + blockIdx.x] = s * wb;
  }
}

__global__ void __launch_bounds__(256) reduce_kernel(
    const float* __restrict__ partial, float* __restrict__ out) {
  int tid = threadIdx.x;
  float acc = 0.0f;
  for (int i = tid; i < NBLK; i += 256) acc += partial[i];
#pragma unroll
  for (int off = 32; off > 0; off >>= 1) acc += __shfl_down(acc, off, 64);
  __shared__ float wsum[4];
  int lane = tid & 63, wave = tid >> 6;
  if (lane == 0) wsum[wave] = acc;
  __syncthreads();
  if (tid == 0) {
    float s = (wsum[0] + wsum[1]) + (wsum[2] + wsum[3]);
    out[0] = s * OUT_SCALE;
  }
}

extern "C" void kernel_launch(void* const* d_in, const int* in_sizes, int n_in,
                              void* d_out, int out_size, void* d_ws, size_t ws_size,
                              hipStream_t stream) {
  const float* images = (const float*)d_in[0];
  const float* segs = (const float*)d_in[1];
  const float* rois = (const float*)d_in[2];
  const float* labels = (const float*)d_in[3];
  float* out = (float*)d_out;

  char* ws = (char*)d_ws;
  _Float16* comb = (_Float16*)ws;                                  // 1 MB
  float* gate = (float*)(ws + (size_t)N_ * P_ * 32 * 2);           // 64 KB
  float* partial = (float*)(ws + (size_t)N_ * P_ * 32 * 2 +
                            (size_t)N_ * P_ * sizeof(float));      // 8.25 KB

  prep_kernel<<<dim3(N_ * P_ / 64), dim3(64), 0, stream>>>(
      images, segs, rois, labels, comb, gate);
  energy_kernel<<<dim3(NTRI, N_), dim3(256), 0, stream>>>(comb, gate, partial);
  reduce_kernel<<<dim3(1), dim3(256), 0, stream>>>(partial, out);
}